// Round 1
// baseline (748.038 us; speedup 1.0000x reference)
//
#include <hip/hip_runtime.h>
#include <hip/hip_bf16.h>

#define NB   4
#define C    256
#define NPIX 4096
#define EPSV 1e-5f
#define SCL  0.0625f   // C^-0.5

typedef __bf16 bf16x8 __attribute__((ext_vector_type(8)));
typedef float  f32x4  __attribute__((ext_vector_type(4)));
typedef __hip_bfloat16 bf16;

// ---------------------------------------------------------------------------
// Kernel 1: transpose fp32 [C][N] -> bf16 [N][C], fused gate partial sums
// grid (N/64, C/64, B*2), block 256
// ---------------------------------------------------------------------------
__global__ __launch_bounds__(256) void k_transpose(
    const float* __restrict__ x1, const float* __restrict__ x2,
    const float* __restrict__ gate_w,
    bf16* __restrict__ xt1, bf16* __restrict__ xt2, float* __restrict__ gate_ws)
{
    __shared__ float tile[64][65];
    const int nt = blockIdx.x, ct = blockIdx.y, z = blockIdx.z;
    const int b = z >> 1, which = z & 1;
    const float* x = which ? x2 : x1;
    bf16* xt = which ? xt2 : xt1;
    const int t = threadIdx.x;
    const int n0 = nt * 64, c0 = ct * 64;

    const float* xp = x + ((size_t)b * C + c0) * NPIX + n0;
#pragma unroll
    for (int i = 0; i < 16; ++i) {
        int cl = (t >> 6) + i * 4, nl = t & 63;
        tile[cl][nl] = xp[(size_t)cl * NPIX + nl];
    }
    __syncthreads();

    // gate partial: each of 4 thread-quarters sums 16 channels for one pixel
    {
        int nl = t & 63, q = t >> 6;
        float s = 0.f;
#pragma unroll
        for (int i = 0; i < 16; ++i) {
            int cl = q * 16 + i;
            s += tile[cl][nl] * gate_w[which * C + c0 + cl];
        }
        atomicAdd(&gate_ws[b * NPIX + n0 + nl], s);
    }

    bf16* xtp = xt + ((size_t)b * NPIX + n0) * C + c0;
#pragma unroll
    for (int i = 0; i < 16; ++i) {
        int nl = (t >> 6) + i * 4, cl = t & 63;
        xtp[(size_t)nl * C + cl] = __float2bfloat16(tile[cl][nl]);
    }
}

// ---------------------------------------------------------------------------
// Kernel 2: QKV projections via bf16 MFMA.
// Qt,Kt stored [B][N][C]; V stored [B][C][N]. Bias added in epilogue.
// grid (N/64, C/64, B*3), block 256 (4 waves, each 16n x 64o)
// ---------------------------------------------------------------------------
__global__ __launch_bounds__(256) void k_qkv(
    const bf16* __restrict__ xt1, const bf16* __restrict__ xt2,
    const float* __restrict__ qw, const float* __restrict__ qb,
    const float* __restrict__ kw, const float* __restrict__ kb,
    const float* __restrict__ vw, const float* __restrict__ vb,
    bf16* __restrict__ Qt, bf16* __restrict__ Kt, bf16* __restrict__ Vv)
{
    const int nt = blockIdx.x, ot = blockIdx.y, zp = blockIdx.z;
    const int b = zp / 3, pidx = zp % 3;
    const bf16* xt = (pidx == 0) ? xt1 : xt2;
    const float* w    = (pidx == 0) ? qw : (pidx == 1) ? kw : vw;
    const float* bias = (pidx == 0) ? qb : (pidx == 1) ? kb : vb;

    const int wave = threadIdx.x >> 6, lane = threadIdx.x & 63;
    const int g = lane >> 4, l15 = lane & 15;
    const int n0 = nt * 64 + wave * 16;
    const int o0 = ot * 64;

    // A-frags from xt: rows = n (lane&15), k = 8 contiguous c
    bf16x8 a[8];
    const bf16* xrow = xt + ((size_t)b * NPIX + n0 + l15) * C;
#pragma unroll
    for (int cb = 0; cb < 8; ++cb)
        a[cb] = *reinterpret_cast<const bf16x8*>(xrow + cb * 32 + 8 * g);

#pragma unroll
    for (int os = 0; os < 4; ++os) {
        const int oo = o0 + os * 16;
        const float* wrow = w + (size_t)(oo + l15) * C;
        f32x4 acc = {0.f, 0.f, 0.f, 0.f};
#pragma unroll
        for (int cb = 0; cb < 8; ++cb) {
            const float4* wp = reinterpret_cast<const float4*>(wrow + cb * 32 + 8 * g);
            float4 w0 = wp[0], w1 = wp[1];
            bf16x8 bfrag = { (__bf16)w0.x, (__bf16)w0.y, (__bf16)w0.z, (__bf16)w0.w,
                             (__bf16)w1.x, (__bf16)w1.y, (__bf16)w1.z, (__bf16)w1.w };
            if (pidx < 2)
                acc = __builtin_amdgcn_mfma_f32_16x16x32_bf16(a[cb], bfrag, acc, 0, 0, 0);
            else
                acc = __builtin_amdgcn_mfma_f32_16x16x32_bf16(bfrag, a[cb], acc, 0, 0, 0);
        }
        if (pidx < 2) {
            // D[n=4g+r][o=l15] -> (Qt|Kt)[b][n0+4g+r][oo+l15]
            float bv = bias[oo + l15];
            bf16* dst = ((pidx == 0) ? Qt : Kt) + ((size_t)b * NPIX + n0 + 4 * g) * C + oo + l15;
#pragma unroll
            for (int r = 0; r < 4; ++r)
                dst[(size_t)r * C] = __float2bfloat16(acc[r] + bv);
        } else {
            // D[o=4g+r][n=l15] -> V[b][oo+4g+r][n0+l15]
            bf16* dst = Vv + ((size_t)b * C + oo + 4 * g) * NPIX + n0 + l15;
#pragma unroll
            for (int r = 0; r < 4; ++r)
                dst[(size_t)r * NPIX] = __float2bfloat16(acc[r] + bias[oo + 4 * g + r]);
        }
    }
}

// ---------------------------------------------------------------------------
// Kernel 3: flash attention. Each wave owns 16 query rows, KV tile = 32.
// Qt,Kt: [B][N][C] bf16; V: [B][C][N] bf16; Ot out: [B][N][C] bf16.
// grid (N/64, B), block 256 (4 waves)
// ---------------------------------------------------------------------------
__global__ __launch_bounds__(256) void k_attn(
    const bf16* __restrict__ Qt, const bf16* __restrict__ Kt,
    const bf16* __restrict__ Vv, bf16* __restrict__ Ot)
{
    const int b = blockIdx.y;
    const int wave = threadIdx.x >> 6, lane = threadIdx.x & 63;
    const int g = lane >> 4, l15 = lane & 15;
    const int n0 = blockIdx.x * 64 + wave * 16;

    __shared__ bf16 plds[4][16][56];   // stride 56 -> 112B rows (16B aligned, ~2-way banks)

    bf16x8 q[8];
    const bf16* qrow = Qt + ((size_t)b * NPIX + n0 + l15) * C;
#pragma unroll
    for (int cb = 0; cb < 8; ++cb)
        q[cb] = *reinterpret_cast<const bf16x8*>(qrow + cb * 32 + 8 * g);

    f32x4 o[16];
#pragma unroll
    for (int i = 0; i < 16; ++i) o[i] = {0.f, 0.f, 0.f, 0.f};
    float m_run[4], l_run[4];
#pragma unroll
    for (int r = 0; r < 4; ++r) { m_run[r] = -1e30f; l_run[r] = 0.f; }

    for (int m0 = 0; m0 < NPIX; m0 += 32) {
        // S = Qt * Kt^T (two 16-col tiles)
        f32x4 s[2] = {{0.f,0.f,0.f,0.f},{0.f,0.f,0.f,0.f}};
#pragma unroll
        for (int mt = 0; mt < 2; ++mt) {
            const bf16* krow = Kt + ((size_t)b * NPIX + m0 + mt * 16 + l15) * C;
#pragma unroll
            for (int cb = 0; cb < 8; ++cb) {
                bf16x8 kf = *reinterpret_cast<const bf16x8*>(krow + cb * 32 + 8 * g);
                s[mt] = __builtin_amdgcn_mfma_f32_16x16x32_bf16(q[cb], kf, s[mt], 0, 0, 0);
            }
        }
        // online softmax over the 32 columns; row of D = 4g+r, col = l15
        float corr[4];
#pragma unroll
        for (int r = 0; r < 4; ++r) {
            float v0 = s[0][r] * SCL, v1 = s[1][r] * SCL;
            float mx = fmaxf(v0, v1);
            mx = fmaxf(mx, __shfl_xor(mx, 1));
            mx = fmaxf(mx, __shfl_xor(mx, 2));
            mx = fmaxf(mx, __shfl_xor(mx, 4));
            mx = fmaxf(mx, __shfl_xor(mx, 8));
            float mnew = fmaxf(m_run[r], mx);
            float c  = __expf(m_run[r] - mnew);
            float p0 = __expf(v0 - mnew), p1 = __expf(v1 - mnew);
            float sum = p0 + p1;
            sum += __shfl_xor(sum, 1);
            sum += __shfl_xor(sum, 2);
            sum += __shfl_xor(sum, 4);
            sum += __shfl_xor(sum, 8);
            l_run[r] = l_run[r] * c + sum;
            m_run[r] = mnew;
            corr[r] = c;
            s[0][r] = p0; s[1][r] = p1;
        }
#pragma unroll
        for (int i = 0; i < 16; ++i)
#pragma unroll
            for (int r = 0; r < 4; ++r) o[i][r] *= corr[r];

        // P: D-layout -> A-layout via LDS (per-wave private buffer)
#pragma unroll
        for (int mt = 0; mt < 2; ++mt)
#pragma unroll
            for (int r = 0; r < 4; ++r)
                plds[wave][4 * g + r][mt * 16 + l15] = __float2bfloat16(s[mt][r]);
        __syncthreads();
        bf16x8 pf = *reinterpret_cast<const bf16x8*>(&plds[wave][l15][8 * g]);

        // O += P * V^T
#pragma unroll
        for (int ct = 0; ct < 16; ++ct) {
            const bf16* vrow = Vv + ((size_t)b * C + ct * 16 + l15) * NPIX + m0 + 8 * g;
            bf16x8 vf = *reinterpret_cast<const bf16x8*>(vrow);
            o[ct] = __builtin_amdgcn_mfma_f32_16x16x32_bf16(pf, vf, o[ct], 0, 0, 0);
        }
        __syncthreads();
    }

    // normalize + store Ot[b][n][c]
#pragma unroll
    for (int ct = 0; ct < 16; ++ct) {
        bf16* dst = Ot + ((size_t)b * NPIX + n0 + 4 * g) * C + ct * 16 + l15;
#pragma unroll
        for (int r = 0; r < 4; ++r)
            dst[(size_t)r * C] = __float2bfloat16(o[ct][r] / l_run[r]);
    }
}

// ---------------------------------------------------------------------------
// Kernel 4: proj GEMM + BN + ReLU + gate + residual. Out fp32 [B][C][N].
// grid (N/64, C/64, B), block 256 (4 waves each own 16 o-rows; ns loop over 64 n)
// ---------------------------------------------------------------------------
__global__ __launch_bounds__(256) void k_proj(
    const bf16* __restrict__ Ot, const float* __restrict__ pw,
    const float* __restrict__ pb, const float* __restrict__ bn_g,
    const float* __restrict__ bn_b, const float* __restrict__ bn_m,
    const float* __restrict__ bn_v, const float* __restrict__ gate_ws,
    const float* __restrict__ gate_b, const float* __restrict__ x1,
    float* __restrict__ out)
{
    const int nt = blockIdx.x, otile = blockIdx.y, b = blockIdx.z;
    const int wave = threadIdx.x >> 6, lane = threadIdx.x & 63;
    const int g = lane >> 4, l15 = lane & 15;
    const int o0 = otile * 64 + wave * 16;

    // A-frags from proj_w rows (fp32 -> bf16)
    bf16x8 a[8];
    const float* wrow = pw + (size_t)(o0 + l15) * C;
#pragma unroll
    for (int cb = 0; cb < 8; ++cb) {
        const float4* wp = reinterpret_cast<const float4*>(wrow + cb * 32 + 8 * g);
        float4 w0 = wp[0], w1 = wp[1];
        bf16x8 t = { (__bf16)w0.x, (__bf16)w0.y, (__bf16)w0.z, (__bf16)w0.w,
                     (__bf16)w1.x, (__bf16)w1.y, (__bf16)w1.z, (__bf16)w1.w };
        a[cb] = t;
    }
    const float gb = gate_b[0];

#pragma unroll
    for (int ns = 0; ns < 4; ++ns) {
        const int n0 = nt * 64 + ns * 16;
        f32x4 acc = {0.f, 0.f, 0.f, 0.f};
        const bf16* orow = Ot + ((size_t)b * NPIX + n0 + l15) * C;
#pragma unroll
        for (int cb = 0; cb < 8; ++cb) {
            bf16x8 bf = *reinterpret_cast<const bf16x8*>(orow + cb * 32 + 8 * g);
            acc = __builtin_amdgcn_mfma_f32_16x16x32_bf16(a[cb], bf, acc, 0, 0, 0);
        }
        // D[o=4g+r][n=l15]
        float gsum = gate_ws[b * NPIX + n0 + l15];
        float gate = 1.f / (1.f + __expf(-(gsum + gb)));
#pragma unroll
        for (int r = 0; r < 4; ++r) {
            int oc = o0 + 4 * g + r;
            float scl = bn_g[oc] * rsqrtf(bn_v[oc] + EPSV);
            float v = (acc[r] + pb[oc] - bn_m[oc]) * scl + bn_b[oc];
            v = fmaxf(v, 0.f);
            size_t idx = ((size_t)b * C + oc) * NPIX + n0 + l15;
            out[idx] = x1[idx] + gate * v;
        }
    }
}

// ---------------------------------------------------------------------------
extern "C" void kernel_launch(void* const* d_in, const int* in_sizes, int n_in,
                              void* d_out, int out_size, void* d_ws, size_t ws_size,
                              hipStream_t stream)
{
    const float* x1  = (const float*)d_in[0];
    const float* x2  = (const float*)d_in[1];
    const float* q_w = (const float*)d_in[2];
    const float* q_b = (const float*)d_in[3];
    const float* k_w = (const float*)d_in[4];
    const float* k_b = (const float*)d_in[5];
    const float* v_w = (const float*)d_in[6];
    const float* v_b = (const float*)d_in[7];
    const float* p_w = (const float*)d_in[8];
    const float* p_b = (const float*)d_in[9];
    const float* bn_g = (const float*)d_in[10];
    const float* bn_b = (const float*)d_in[11];
    const float* bn_m = (const float*)d_in[12];
    const float* bn_v = (const float*)d_in[13];
    const float* g_w  = (const float*)d_in[14];
    const float* g_b  = (const float*)d_in[15];
    float* out = (float*)d_out;

    const size_t szBF = (size_t)NB * NPIX * C * sizeof(bf16);   // 8 MiB
    char* p = (char*)d_ws;
    bf16* xt1 = (bf16*)p; p += szBF;
    bf16* xt2 = (bf16*)p; p += szBF;
    bf16* Qt  = (bf16*)p; p += szBF;
    bf16* Kt  = (bf16*)p; p += szBF;
    bf16* Vv  = (bf16*)p; p += szBF;
    float* gate_ws = (float*)p;
    bf16* Ot = xt1;   // xt1 is dead after k_qkv

    hipMemsetAsync(gate_ws, 0, (size_t)NB * NPIX * sizeof(float), stream);
    k_transpose<<<dim3(64, 4, 8),  256, 0, stream>>>(x1, x2, g_w, xt1, xt2, gate_ws);
    k_qkv     <<<dim3(64, 4, 12), 256, 0, stream>>>(xt1, xt2, q_w, q_b, k_w, k_b,
                                                    v_w, v_b, Qt, Kt, Vv);
    k_attn    <<<dim3(64, 4),     256, 0, stream>>>(Qt, Kt, Vv, Ot);
    k_proj    <<<dim3(64, 4, 4),  256, 0, stream>>>(Ot, p_w, p_b, bn_g, bn_b, bn_m,
                                                    bn_v, gate_ws, g_b, x1, out);
}

// Round 2
// 304.015 us; speedup vs baseline: 2.4605x; 2.4605x over previous
//
#include <hip/hip_runtime.h>
#include <hip/hip_bf16.h>

#define NB   4
#define C    256
#define NPIX 4096
#define EPSV 1e-5f
#define K2   0.09016844f   // C^-0.5 * log2(e): softmax done in exp2 domain
#define KVB  64
#define NSTEP (NPIX / KVB)

typedef __bf16 bf16x8 __attribute__((ext_vector_type(8)));
typedef float  f32x4  __attribute__((ext_vector_type(4)));
typedef __hip_bfloat16 bf16;

// ---------------------------------------------------------------------------
// Kernel 1: transpose fp32 [C][N] -> bf16 [N][C], fused gate partial sums
// ---------------------------------------------------------------------------
__global__ __launch_bounds__(256) void k_transpose(
    const float* __restrict__ x1, const float* __restrict__ x2,
    const float* __restrict__ gate_w,
    bf16* __restrict__ xt1, bf16* __restrict__ xt2, float* __restrict__ gate_ws)
{
    __shared__ float tile[64][65];
    const int nt = blockIdx.x, ct = blockIdx.y, z = blockIdx.z;
    const int b = z >> 1, which = z & 1;
    const float* x = which ? x2 : x1;
    bf16* xt = which ? xt2 : xt1;
    const int t = threadIdx.x;
    const int n0 = nt * 64, c0 = ct * 64;

    const float* xp = x + ((size_t)b * C + c0) * NPIX + n0;
#pragma unroll
    for (int i = 0; i < 16; ++i) {
        int cl = (t >> 6) + i * 4, nl = t & 63;
        tile[cl][nl] = xp[(size_t)cl * NPIX + nl];
    }
    __syncthreads();

    {
        int nl = t & 63, q = t >> 6;
        float s = 0.f;
#pragma unroll
        for (int i = 0; i < 16; ++i) {
            int cl = q * 16 + i;
            s += tile[cl][nl] * gate_w[which * C + c0 + cl];
        }
        atomicAdd(&gate_ws[b * NPIX + n0 + nl], s);
    }

    bf16* xtp = xt + ((size_t)b * NPIX + n0) * C + c0;
#pragma unroll
    for (int i = 0; i < 16; ++i) {
        int nl = (t >> 6) + i * 4, cl = t & 63;
        xtp[(size_t)nl * C + cl] = __float2bfloat16(tile[cl][nl]);
    }
}

// ---------------------------------------------------------------------------
// Kernel 2: QKV projections via bf16 MFMA (unchanged from R1)
// ---------------------------------------------------------------------------
__global__ __launch_bounds__(256) void k_qkv(
    const bf16* __restrict__ xt1, const bf16* __restrict__ xt2,
    const float* __restrict__ qw, const float* __restrict__ qb,
    const float* __restrict__ kw, const float* __restrict__ kb,
    const float* __restrict__ vw, const float* __restrict__ vb,
    bf16* __restrict__ Qt, bf16* __restrict__ Kt, bf16* __restrict__ Vv)
{
    const int nt = blockIdx.x, ot = blockIdx.y, zp = blockIdx.z;
    const int b = zp / 3, pidx = zp % 3;
    const bf16* xt = (pidx == 0) ? xt1 : xt2;
    const float* w    = (pidx == 0) ? qw : (pidx == 1) ? kw : vw;
    const float* bias = (pidx == 0) ? qb : (pidx == 1) ? kb : vb;

    const int wave = threadIdx.x >> 6, lane = threadIdx.x & 63;
    const int g = lane >> 4, l15 = lane & 15;
    const int n0 = nt * 64 + wave * 16;
    const int o0 = ot * 64;

    bf16x8 a[8];
    const bf16* xrow = xt + ((size_t)b * NPIX + n0 + l15) * C;
#pragma unroll
    for (int cb = 0; cb < 8; ++cb)
        a[cb] = *reinterpret_cast<const bf16x8*>(xrow + cb * 32 + 8 * g);

#pragma unroll
    for (int os = 0; os < 4; ++os) {
        const int oo = o0 + os * 16;
        const float* wrow = w + (size_t)(oo + l15) * C;
        f32x4 acc = {0.f, 0.f, 0.f, 0.f};
#pragma unroll
        for (int cb = 0; cb < 8; ++cb) {
            const float4* wp = reinterpret_cast<const float4*>(wrow + cb * 32 + 8 * g);
            float4 w0 = wp[0], w1 = wp[1];
            bf16x8 bfrag = { (__bf16)w0.x, (__bf16)w0.y, (__bf16)w0.z, (__bf16)w0.w,
                             (__bf16)w1.x, (__bf16)w1.y, (__bf16)w1.z, (__bf16)w1.w };
            if (pidx < 2)
                acc = __builtin_amdgcn_mfma_f32_16x16x32_bf16(a[cb], bfrag, acc, 0, 0, 0);
            else
                acc = __builtin_amdgcn_mfma_f32_16x16x32_bf16(bfrag, a[cb], acc, 0, 0, 0);
        }
        if (pidx < 2) {
            float bv = bias[oo + l15];
            bf16* dst = ((pidx == 0) ? Qt : Kt) + ((size_t)b * NPIX + n0 + 4 * g) * C + oo + l15;
#pragma unroll
            for (int r = 0; r < 4; ++r)
                dst[(size_t)r * C] = __float2bfloat16(acc[r] + bv);
        } else {
            bf16* dst = Vv + ((size_t)b * C + oo + 4 * g) * NPIX + n0 + l15;
#pragma unroll
            for (int r = 0; r < 4; ++r)
                dst[(size_t)r * NPIX] = __float2bfloat16(acc[r] + bias[oo + 4 * g + r]);
        }
    }
}

// ---------------------------------------------------------------------------
// Kernel 3: flash attention v2.
// 4 waves x 16 q-rows = 64 q-rows/block; KVBLK=64; K,V double-buffered in
// 140KB dynamic LDS via global_load_lds(16B) with XOR-swizzled sources
// (linear dest + inverse-swizzled src + swizzled read). One barrier/step.
// exp2-domain online softmax with defer-max (THR=8 log2).
// ---------------------------------------------------------------------------
#define SMEM_BYTES 140288   // K dbuf 2x32KB + V dbuf 2x32KB + P 4x2304B

__device__ __forceinline__ void gload_lds16(const void* g, void* l) {
    __builtin_amdgcn_global_load_lds(
        (const __attribute__((address_space(1))) void*)g,
        (__attribute__((address_space(3))) void*)l, 16, 0, 0);
}

__global__ __launch_bounds__(256, 1) void k_attn(
    const bf16* __restrict__ Qt, const bf16* __restrict__ Kt,
    const bf16* __restrict__ Vv, bf16* __restrict__ Ot)
{
    extern __shared__ __align__(16) char smem[];
    const int b = blockIdx.y;
    const int wave = threadIdx.x >> 6, lane = threadIdx.x & 63;
    const int g = lane >> 4, l15 = lane & 15;
    const int n0 = blockIdx.x * 64 + wave * 16;

    char* Pl = smem + 131072 + wave * 2304;          // [16 rows][144B]

    // staging lane coords
    const int k_mloc = lane >> 5, k_slot = lane & 31;  // K instr: 2 rows x 32 slots
    const int v_cloc = lane >> 3, v_slot = lane & 7;   // V instr: 8 rows x 8 slots

    const bf16* Kg = Kt + (size_t)b * NPIX * C;        // [N][C]
    const bf16* Vg = Vv + (size_t)b * C * NPIX;        // [C][N]

    bf16x8 q[8];
    const bf16* qrow = Qt + ((size_t)b * NPIX + n0 + l15) * C;
#pragma unroll
    for (int cb = 0; cb < 8; ++cb)
        q[cb] = *reinterpret_cast<const bf16x8*>(qrow + cb * 32 + 8 * g);

    f32x4 o[16];
#pragma unroll
    for (int i = 0; i < 16; ++i) o[i] = {0.f, 0.f, 0.f, 0.f};
    float m_run[4], l_run[4];
#pragma unroll
    for (int r = 0; r < 4; ++r) { m_run[r] = -3.0e38f; l_run[r] = 0.f; }

    auto stage = [&](int buf, int m0) {
        char* kd = smem + buf * 32768;
#pragma unroll
        for (int ii = 0; ii < 8; ++ii) {
            const int i = wave * 8 + ii;
            const int m = 2 * i + k_mloc;
            gload_lds16(Kg + ((size_t)(m0 + m)) * C + (k_slot ^ (m & 7)) * 8,
                        kd + i * 1024);
        }
        char* vd = smem + 65536 + buf * 32768;
#pragma unroll
        for (int ii = 0; ii < 8; ++ii) {
            const int i = wave * 8 + ii;
            const int c = 8 * i + v_cloc;
            gload_lds16(Vg + (size_t)c * NPIX + m0 + (v_slot ^ (c & 7)) * 8,
                        vd + i * 1024);
        }
    };

    stage(0, 0);
    asm volatile("s_waitcnt vmcnt(0)" ::: "memory");
    __syncthreads();

    for (int t = 0; t < NSTEP; ++t) {
        const int buf = t & 1;
        if (t + 1 < NSTEP) stage(buf ^ 1, (t + 1) * KVB);

        const char* Kl = smem + buf * 32768;           // [64 rows][512B]
        const char* Vl = smem + 65536 + buf * 32768;   // [256 rows][128B]

        // ---- QK^T: 4 tiles of 16 cols ----
        f32x4 s[4];
#pragma unroll
        for (int tt = 0; tt < 4; ++tt) s[tt] = {0.f, 0.f, 0.f, 0.f};
#pragma unroll
        for (int tt = 0; tt < 4; ++tt) {
            const int m = tt * 16 + l15;
            const char* krow = Kl + m * 512;
            const int sw = (m & 7) * 16;
#pragma unroll
            for (int cb = 0; cb < 8; ++cb) {
                bf16x8 kf = *reinterpret_cast<const bf16x8*>(krow + (((cb * 4 + g) * 16) ^ sw));
                s[tt] = __builtin_amdgcn_mfma_f32_16x16x32_bf16(q[cb], kf, s[tt], 0, 0, 0);
            }
        }

        // ---- online softmax (exp2 domain), defer-max rescale ----
        float rowmax[4];
#pragma unroll
        for (int r = 0; r < 4; ++r) {
            float v0 = s[0][r] * K2, v1 = s[1][r] * K2;
            float v2 = s[2][r] * K2, v3 = s[3][r] * K2;
            s[0][r] = v0; s[1][r] = v1; s[2][r] = v2; s[3][r] = v3;
            float mx = fmaxf(fmaxf(v0, v1), fmaxf(v2, v3));
            mx = fmaxf(mx, __shfl_xor(mx, 1));
            mx = fmaxf(mx, __shfl_xor(mx, 2));
            mx = fmaxf(mx, __shfl_xor(mx, 4));
            mx = fmaxf(mx, __shfl_xor(mx, 8));
            rowmax[r] = mx;
        }
        bool ok = (rowmax[0] <= m_run[0] + 8.f) & (rowmax[1] <= m_run[1] + 8.f)
                & (rowmax[2] <= m_run[2] + 8.f) & (rowmax[3] <= m_run[3] + 8.f);
        if (!__all(ok)) {
            float cf[4];
#pragma unroll
            for (int r = 0; r < 4; ++r) {
                float mn = fmaxf(m_run[r], rowmax[r]);
                cf[r] = exp2f(m_run[r] - mn);
                m_run[r] = mn;
                l_run[r] *= cf[r];
            }
#pragma unroll
            for (int ct = 0; ct < 16; ++ct)
#pragma unroll
                for (int r = 0; r < 4; ++r) o[ct][r] *= cf[r];
        }
#pragma unroll
        for (int r = 0; r < 4; ++r) {
            float p0 = exp2f(s[0][r] - m_run[r]);
            float p1 = exp2f(s[1][r] - m_run[r]);
            float p2 = exp2f(s[2][r] - m_run[r]);
            float p3 = exp2f(s[3][r] - m_run[r]);
            bf16* prow = (bf16*)(Pl + (4 * g + r) * 144) + l15;
            prow[0]  = __float2bfloat16(p0);
            prow[16] = __float2bfloat16(p1);
            prow[32] = __float2bfloat16(p2);
            prow[48] = __float2bfloat16(p3);
            float sm = (p0 + p1) + (p2 + p3);
            sm += __shfl_xor(sm, 1);
            sm += __shfl_xor(sm, 2);
            sm += __shfl_xor(sm, 4);
            sm += __shfl_xor(sm, 8);
            l_run[r] += sm;
        }

        // ---- PV: O += P * V ----
        const char* Prow = Pl + l15 * 144 + g * 16;
        bf16x8 pf0 = *reinterpret_cast<const bf16x8*>(Prow);
        bf16x8 pf1 = *reinterpret_cast<const bf16x8*>(Prow + 64);
#pragma unroll
        for (int ct = 0; ct < 16; ++ct) {
            const int c = ct * 16 + l15;
            const char* vrow = Vl + c * 128;
            const int sw = (c & 7) * 16;
            bf16x8 vf0 = *reinterpret_cast<const bf16x8*>(vrow + ((g * 16) ^ sw));
            bf16x8 vf1 = *reinterpret_cast<const bf16x8*>(vrow + (((4 + g) * 16) ^ sw));
            o[ct] = __builtin_amdgcn_mfma_f32_16x16x32_bf16(pf0, vf0, o[ct], 0, 0, 0);
            o[ct] = __builtin_amdgcn_mfma_f32_16x16x32_bf16(pf1, vf1, o[ct], 0, 0, 0);
        }

        asm volatile("s_waitcnt vmcnt(0)" ::: "memory");
        __syncthreads();
    }

    float inv[4];
#pragma unroll
    for (int r = 0; r < 4; ++r) inv[r] = 1.0f / l_run[r];
#pragma unroll
    for (int ct = 0; ct < 16; ++ct) {
        bf16* dst = Ot + ((size_t)b * NPIX + n0 + 4 * g) * C + ct * 16 + l15;
#pragma unroll
        for (int r = 0; r < 4; ++r)
            dst[(size_t)r * C] = __float2bfloat16(o[ct][r] * inv[r]);
    }
}

// ---------------------------------------------------------------------------
// Kernel 4: proj GEMM + BN + ReLU + gate + residual (unchanged from R1)
// ---------------------------------------------------------------------------
__global__ __launch_bounds__(256) void k_proj(
    const bf16* __restrict__ Ot, const float* __restrict__ pw,
    const float* __restrict__ pb, const float* __restrict__ bn_g,
    const float* __restrict__ bn_b, const float* __restrict__ bn_m,
    const float* __restrict__ bn_v, const float* __restrict__ gate_ws,
    const float* __restrict__ gate_b, const float* __restrict__ x1,
    float* __restrict__ out)
{
    const int nt = blockIdx.x, otile = blockIdx.y, b = blockIdx.z;
    const int wave = threadIdx.x >> 6, lane = threadIdx.x & 63;
    const int g = lane >> 4, l15 = lane & 15;
    const int o0 = otile * 64 + wave * 16;

    bf16x8 a[8];
    const float* wrow = pw + (size_t)(o0 + l15) * C;
#pragma unroll
    for (int cb = 0; cb < 8; ++cb) {
        const float4* wp = reinterpret_cast<const float4*>(wrow + cb * 32 + 8 * g);
        float4 w0 = wp[0], w1 = wp[1];
        bf16x8 t = { (__bf16)w0.x, (__bf16)w0.y, (__bf16)w0.z, (__bf16)w0.w,
                     (__bf16)w1.x, (__bf16)w1.y, (__bf16)w1.z, (__bf16)w1.w };
        a[cb] = t;
    }
    const float gb = gate_b[0];

#pragma unroll
    for (int ns = 0; ns < 4; ++ns) {
        const int n0 = nt * 64 + ns * 16;
        f32x4 acc = {0.f, 0.f, 0.f, 0.f};
        const bf16* orow = Ot + ((size_t)b * NPIX + n0 + l15) * C;
#pragma unroll
        for (int cb = 0; cb < 8; ++cb) {
            bf16x8 bf = *reinterpret_cast<const bf16x8*>(orow + cb * 32 + 8 * g);
            acc = __builtin_amdgcn_mfma_f32_16x16x32_bf16(a[cb], bf, acc, 0, 0, 0);
        }
        float gsum = gate_ws[b * NPIX + n0 + l15];
        float gate = 1.f / (1.f + __expf(-(gsum + gb)));
#pragma unroll
        for (int r = 0; r < 4; ++r) {
            int oc = o0 + 4 * g + r;
            float scl = bn_g[oc] * rsqrtf(bn_v[oc] + EPSV);
            float v = (acc[r] + pb[oc] - bn_m[oc]) * scl + bn_b[oc];
            v = fmaxf(v, 0.f);
            size_t idx = ((size_t)b * C + oc) * NPIX + n0 + l15;
            out[idx] = x1[idx] + gate * v;
        }
    }
}

// ---------------------------------------------------------------------------
extern "C" void kernel_launch(void* const* d_in, const int* in_sizes, int n_in,
                              void* d_out, int out_size, void* d_ws, size_t ws_size,
                              hipStream_t stream)
{
    const float* x1  = (const float*)d_in[0];
    const float* x2  = (const float*)d_in[1];
    const float* q_w = (const float*)d_in[2];
    const float* q_b = (const float*)d_in[3];
    const float* k_w = (const float*)d_in[4];
    const float* k_b = (const float*)d_in[5];
    const float* v_w = (const float*)d_in[6];
    const float* v_b = (const float*)d_in[7];
    const float* p_w = (const float*)d_in[8];
    const float* p_b = (const float*)d_in[9];
    const float* bn_g = (const float*)d_in[10];
    const float* bn_b = (const float*)d_in[11];
    const float* bn_m = (const float*)d_in[12];
    const float* bn_v = (const float*)d_in[13];
    const float* g_w  = (const float*)d_in[14];
    const float* g_b  = (const float*)d_in[15];
    float* out = (float*)d_out;

    const size_t szBF = (size_t)NB * NPIX * C * sizeof(bf16);   // 8 MiB
    char* p = (char*)d_ws;
    bf16* xt1 = (bf16*)p; p += szBF;
    bf16* xt2 = (bf16*)p; p += szBF;
    bf16* Qt  = (bf16*)p; p += szBF;
    bf16* Kt  = (bf16*)p; p += szBF;
    bf16* Vv  = (bf16*)p; p += szBF;
    float* gate_ws = (float*)p;
    bf16* Ot = xt1;   // xt1 dead after k_qkv

    hipFuncSetAttribute((const void*)k_attn,
                        hipFuncAttributeMaxDynamicSharedMemorySize, SMEM_BYTES);

    hipMemsetAsync(gate_ws, 0, (size_t)NB * NPIX * sizeof(float), stream);
    k_transpose<<<dim3(64, 4, 8),  256, 0, stream>>>(x1, x2, g_w, xt1, xt2, gate_ws);
    k_qkv     <<<dim3(64, 4, 12), 256, 0, stream>>>(xt1, xt2, q_w, q_b, k_w, k_b,
                                                    v_w, v_b, Qt, Kt, Vv);
    k_attn    <<<dim3(64, 4), 256, SMEM_BYTES, stream>>>(Qt, Kt, Vv, Ot);
    k_proj    <<<dim3(64, 4, 4),  256, 0, stream>>>(Ot, p_w, p_b, bn_g, bn_b, bn_m,
                                                    bn_v, gate_ws, g_b, x1, out);
}

// Round 3
// 257.326 us; speedup vs baseline: 2.9070x; 1.1814x over previous
//
#include <hip/hip_runtime.h>
#include <hip/hip_bf16.h>

#define NB   4
#define C    256
#define NPIX 4096
#define EPSV 1e-5f
#define K2   0.09016844f   // C^-0.5 * log2(e): softmax in exp2 domain
#define KVB  32
#define NKVH 2048          // kv per block (half)
#define NSTEPH (NKVH / KVB)

typedef __bf16 bf16x8 __attribute__((ext_vector_type(8)));
typedef float  f32x4  __attribute__((ext_vector_type(4)));
typedef __hip_bfloat16 bf16;

// ---------------------------------------------------------------------------
// Kernel 1: transpose fp32 [C][N] -> bf16 [N][C], fused gate partial sums
// ---------------------------------------------------------------------------
__global__ __launch_bounds__(256) void k_transpose(
    const float* __restrict__ x1, const float* __restrict__ x2,
    const float* __restrict__ gate_w,
    bf16* __restrict__ xt1, bf16* __restrict__ xt2, float* __restrict__ gate_ws)
{
    __shared__ float tile[64][65];
    const int nt = blockIdx.x, ct = blockIdx.y, z = blockIdx.z;
    const int b = z >> 1, which = z & 1;
    const float* x = which ? x2 : x1;
    bf16* xt = which ? xt2 : xt1;
    const int t = threadIdx.x;
    const int n0 = nt * 64, c0 = ct * 64;

    const float* xp = x + ((size_t)b * C + c0) * NPIX + n0;
#pragma unroll
    for (int i = 0; i < 16; ++i) {
        int cl = (t >> 6) + i * 4, nl = t & 63;
        tile[cl][nl] = xp[(size_t)cl * NPIX + nl];
    }
    __syncthreads();

    {
        int nl = t & 63, q = t >> 6;
        float s = 0.f;
#pragma unroll
        for (int i = 0; i < 16; ++i) {
            int cl = q * 16 + i;
            s += tile[cl][nl] * gate_w[which * C + c0 + cl];
        }
        atomicAdd(&gate_ws[b * NPIX + n0 + nl], s);
    }

    bf16* xtp = xt + ((size_t)b * NPIX + n0) * C + c0;
#pragma unroll
    for (int i = 0; i < 16; ++i) {
        int nl = (t >> 6) + i * 4, cl = t & 63;
        xtp[(size_t)nl * C + cl] = __float2bfloat16(tile[cl][nl]);
    }
}

// ---------------------------------------------------------------------------
// Kernel 2: QKV projections via bf16 MFMA (unchanged)
// ---------------------------------------------------------------------------
__global__ __launch_bounds__(256) void k_qkv(
    const bf16* __restrict__ xt1, const bf16* __restrict__ xt2,
    const float* __restrict__ qw, const float* __restrict__ qb,
    const float* __restrict__ kw, const float* __restrict__ kb,
    const float* __restrict__ vw, const float* __restrict__ vb,
    bf16* __restrict__ Qt, bf16* __restrict__ Kt, bf16* __restrict__ Vv)
{
    const int nt = blockIdx.x, ot = blockIdx.y, zp = blockIdx.z;
    const int b = zp / 3, pidx = zp % 3;
    const bf16* xt = (pidx == 0) ? xt1 : xt2;
    const float* w    = (pidx == 0) ? qw : (pidx == 1) ? kw : vw;
    const float* bias = (pidx == 0) ? qb : (pidx == 1) ? kb : vb;

    const int wave = threadIdx.x >> 6, lane = threadIdx.x & 63;
    const int g = lane >> 4, l15 = lane & 15;
    const int n0 = nt * 64 + wave * 16;
    const int o0 = ot * 64;

    bf16x8 a[8];
    const bf16* xrow = xt + ((size_t)b * NPIX + n0 + l15) * C;
#pragma unroll
    for (int cb = 0; cb < 8; ++cb)
        a[cb] = *reinterpret_cast<const bf16x8*>(xrow + cb * 32 + 8 * g);

#pragma unroll
    for (int os = 0; os < 4; ++os) {
        const int oo = o0 + os * 16;
        const float* wrow = w + (size_t)(oo + l15) * C;
        f32x4 acc = {0.f, 0.f, 0.f, 0.f};
#pragma unroll
        for (int cb = 0; cb < 8; ++cb) {
            const float4* wp = reinterpret_cast<const float4*>(wrow + cb * 32 + 8 * g);
            float4 w0 = wp[0], w1 = wp[1];
            bf16x8 bfrag = { (__bf16)w0.x, (__bf16)w0.y, (__bf16)w0.z, (__bf16)w0.w,
                             (__bf16)w1.x, (__bf16)w1.y, (__bf16)w1.z, (__bf16)w1.w };
            if (pidx < 2)
                acc = __builtin_amdgcn_mfma_f32_16x16x32_bf16(a[cb], bfrag, acc, 0, 0, 0);
            else
                acc = __builtin_amdgcn_mfma_f32_16x16x32_bf16(bfrag, a[cb], acc, 0, 0, 0);
        }
        if (pidx < 2) {
            float bv = bias[oo + l15];
            bf16* dst = ((pidx == 0) ? Qt : Kt) + ((size_t)b * NPIX + n0 + 4 * g) * C + oo + l15;
#pragma unroll
            for (int r = 0; r < 4; ++r)
                dst[(size_t)r * C] = __float2bfloat16(acc[r] + bv);
        } else {
            bf16* dst = Vv + ((size_t)b * C + oo + 4 * g) * NPIX + n0 + l15;
#pragma unroll
            for (int r = 0; r < 4; ++r)
                dst[(size_t)r * NPIX] = __float2bfloat16(acc[r] + bias[oo + 4 * g + r]);
        }
    }
}

// ---------------------------------------------------------------------------
// Kernel 3: flash attention v3 (KV-split x2, swapped QK^T, lane-local softmax)
// ---------------------------------------------------------------------------
#define SMEM_ATTN 70656   // K 2x16K @0, V 2x16K @32768, P 4x1280 @65536

__device__ __forceinline__ void gload16(const void* g, void* l) {
    __builtin_amdgcn_global_load_lds(
        (const __attribute__((address_space(1))) void*)g,
        (__attribute__((address_space(3))) void*)l, 16, 0, 0);
}

__global__ __launch_bounds__(256, 2) void k_attn(
    const bf16* __restrict__ Qt, const bf16* __restrict__ Kt,
    const bf16* __restrict__ Vv, bf16* __restrict__ Opart,
    float2* __restrict__ mlws)
{
    extern __shared__ __align__(16) char smem[];
    const int id = blockIdx.x;
    const int combo = id & 7, nt = id >> 3;     // each XCD -> one (b,half)
    const int b = combo >> 1, half = combo & 1;
    const int m_base = half * NKVH;
    const int wave = threadIdx.x >> 6, lane = threadIdx.x & 63;
    const int g = lane >> 4, l15 = lane & 15;
    const int n0 = nt * 64 + wave * 16;

    char* Pl = smem + 65536 + wave * 1280;      // [16 rows][80B]
    const int k_mloc = lane >> 5, k_slot = lane & 31;
    const int v_cloc = lane >> 2, v_slot = lane & 3;

    const bf16* Kg = Kt + (size_t)b * NPIX * C;   // [N][C]
    const bf16* Vg = Vv + (size_t)b * C * NPIX;   // [C][N]

    bf16x8 q[8];
    const bf16* qrow = Qt + ((size_t)b * NPIX + n0 + l15) * C;
#pragma unroll
    for (int cb = 0; cb < 8; ++cb)
        q[cb] = *reinterpret_cast<const bf16x8*>(qrow + cb * 32 + 8 * g);

    f32x4 o[16];
#pragma unroll
    for (int i = 0; i < 16; ++i) o[i] = {0.f, 0.f, 0.f, 0.f};
    float m_run = -3.0e38f, l_run = 0.f;

    auto stage = [&](int buf, int m0) {
        char* kd = smem + buf * 16384;            // K: [32 rows][512B]
#pragma unroll
        for (int ii = 0; ii < 4; ++ii) {
            const int i = wave * 4 + ii;
            const int m = 2 * i + k_mloc;
            gload16(Kg + ((size_t)(m0 + m)) * C + (k_slot ^ (m & 7)) * 8,
                    kd + i * 1024);
        }
        char* vd = smem + 32768 + buf * 16384;    // V: [256 rows][64B]
#pragma unroll
        for (int ii = 0; ii < 4; ++ii) {
            const int i = wave * 4 + ii;
            const int c = 16 * i + v_cloc;
            gload16(Vg + (size_t)c * NPIX + m0 + (v_slot ^ (c & 3)) * 8,
                    vd + i * 1024);
        }
    };

    stage(0, m_base);
    asm volatile("s_waitcnt vmcnt(0)" ::: "memory");
    __syncthreads();

    for (int t = 0; t < NSTEPH; ++t) {
        const int buf = t & 1;
        if (t + 1 < NSTEPH) stage(buf ^ 1, m_base + (t + 1) * KVB);

        const char* Kl = smem + buf * 16384;
        const char* Vl = smem + 32768 + buf * 16384;

        // ---- QK^T swapped: D[kv][q], 4 independent chains ----
        f32x4 sa[2], sb[2];
#pragma unroll
        for (int tt = 0; tt < 2; ++tt) { sa[tt] = {0,0,0,0}; sb[tt] = {0,0,0,0}; }
        const int sw = (l15 & 7) * 16;
        __builtin_amdgcn_s_setprio(1);
#pragma unroll
        for (int tt = 0; tt < 2; ++tt) {
            const char* krow = Kl + (tt * 16 + l15) * 512;
#pragma unroll
            for (int cb = 0; cb < 4; ++cb) {
                bf16x8 kf = *reinterpret_cast<const bf16x8*>(krow + (((cb * 4 + g) * 16) ^ sw));
                sa[tt] = __builtin_amdgcn_mfma_f32_16x16x32_bf16(kf, q[cb], sa[tt], 0, 0, 0);
            }
#pragma unroll
            for (int cb = 4; cb < 8; ++cb) {
                bf16x8 kf = *reinterpret_cast<const bf16x8*>(krow + (((cb * 4 + g) * 16) ^ sw));
                sb[tt] = __builtin_amdgcn_mfma_f32_16x16x32_bf16(kf, q[cb], sb[tt], 0, 0, 0);
            }
        }
        __builtin_amdgcn_s_setprio(0);

        // ---- softmax: lane owns q=l15; 8 scores (kv = 16tt + 4g + r) ----
        float v8[8];
#pragma unroll
        for (int tt = 0; tt < 2; ++tt)
#pragma unroll
            for (int r = 0; r < 4; ++r)
                v8[tt * 4 + r] = (sa[tt][r] + sb[tt][r]) * K2;
        float mx = fmaxf(fmaxf(fmaxf(v8[0], v8[1]), fmaxf(v8[2], v8[3])),
                         fmaxf(fmaxf(v8[4], v8[5]), fmaxf(v8[6], v8[7])));
        mx = fmaxf(mx, __shfl_xor(mx, 16));
        mx = fmaxf(mx, __shfl_xor(mx, 32));

        if (!__all(mx <= m_run + 8.f)) {
            float mnew = fmaxf(m_run, mx);
            float cf = exp2f(m_run - mnew);
            m_run = mnew;
            l_run *= cf;
            float cfq[4];
#pragma unroll
            for (int r = 0; r < 4; ++r) cfq[r] = __shfl(cf, 4 * g + r);
#pragma unroll
            for (int ct = 0; ct < 16; ++ct)
#pragma unroll
                for (int r = 0; r < 4; ++r) o[ct][r] *= cfq[r];
        }

        bf16 pr[8];
        float p[8];
#pragma unroll
        for (int j = 0; j < 8; ++j) {
            p[j] = exp2f(v8[j] - m_run);
            pr[j] = __float2bfloat16(p[j]);
        }
        float sum = ((p[0] + p[1]) + (p[2] + p[3])) + ((p[4] + p[5]) + (p[6] + p[7]));
        sum += __shfl_xor(sum, 16);
        sum += __shfl_xor(sum, 32);
        l_run += sum;

        // P[q=l15][kv]: cols 4g..4g+3 (+16tt) -> two 8B stores
        *reinterpret_cast<uint64_t*>(Pl + l15 * 80 + 8 * g)      = *reinterpret_cast<uint64_t*>(&pr[0]);
        *reinterpret_cast<uint64_t*>(Pl + l15 * 80 + 8 * g + 32) = *reinterpret_cast<uint64_t*>(&pr[4]);

        // ---- PV: O += P * V ----
        bf16x8 pf = *reinterpret_cast<const bf16x8*>(Pl + l15 * 80 + 16 * g);
        __builtin_amdgcn_s_setprio(1);
#pragma unroll
        for (int ct = 0; ct < 16; ++ct) {
            const int c = ct * 16 + l15;
            bf16x8 vf = *reinterpret_cast<const bf16x8*>(Vl + c * 64 + 16 * (g ^ (c & 3)));
            o[ct] = __builtin_amdgcn_mfma_f32_16x16x32_bf16(pf, vf, o[ct], 0, 0, 0);
        }
        __builtin_amdgcn_s_setprio(0);

        asm volatile("s_waitcnt vmcnt(0)" ::: "memory");
        __syncthreads();
    }

    float invl = 1.0f / l_run;
    float invq[4];
#pragma unroll
    for (int r = 0; r < 4; ++r) invq[r] = __shfl(invl, 4 * g + r);

    const int ph = half * NB + b;
    bf16* dst0 = Opart + ((size_t)ph * NPIX + n0) * C;
#pragma unroll
    for (int ct = 0; ct < 16; ++ct)
#pragma unroll
        for (int r = 0; r < 4; ++r)
            dst0[(size_t)(4 * g + r) * C + ct * 16 + l15] =
                __float2bfloat16(o[ct][r] * invq[r]);
    if (lane < 16)
        mlws[(size_t)ph * NPIX + n0 + l15] = make_float2(m_run, l_run);
}

// ---------------------------------------------------------------------------
// Kernel 3b: combine the two KV halves -> Ot bf16 [B][N][C]
// ---------------------------------------------------------------------------
__global__ __launch_bounds__(256) void k_combine(
    const bf16* __restrict__ Op, const float2* __restrict__ ml,
    bf16* __restrict__ Ot)
{
    const int tid = blockIdx.x * 256 + threadIdx.x;  // 524288 threads
    const int c8 = tid & 31;
    const int rest = tid >> 5;
    const int n = rest & 4095;
    const int b = rest >> 12;

    float2 a0 = ml[(size_t)b * NPIX + n];
    float2 a1 = ml[(size_t)(4 + b) * NPIX + n];
    float M = fmaxf(a0.x, a1.x);
    float w0 = exp2f(a0.x - M) * a0.y;
    float w1 = exp2f(a1.x - M) * a1.y;
    float rs = 1.0f / (w0 + w1);
    w0 *= rs; w1 *= rs;

    const size_t base = ((size_t)b * NPIX + n) * C + c8 * 8;
    bf16x8 x0 = *reinterpret_cast<const bf16x8*>(Op + base);
    bf16x8 x1 = *reinterpret_cast<const bf16x8*>(Op + (size_t)4 * NPIX * C + base);
    bf16 outv[8];
#pragma unroll
    for (int j = 0; j < 8; ++j)
        outv[j] = __float2bfloat16(w0 * (float)x0[j] + w1 * (float)x1[j]);
    *reinterpret_cast<bf16x8*>(Ot + base) = *reinterpret_cast<bf16x8*>(outv);
}

// ---------------------------------------------------------------------------
// Kernel 4: proj GEMM + BN + ReLU + gate + residual (unchanged)
// ---------------------------------------------------------------------------
__global__ __launch_bounds__(256) void k_proj(
    const bf16* __restrict__ Ot, const float* __restrict__ pw,
    const float* __restrict__ pb, const float* __restrict__ bn_g,
    const float* __restrict__ bn_b, const float* __restrict__ bn_m,
    const float* __restrict__ bn_v, const float* __restrict__ gate_ws,
    const float* __restrict__ gate_b, const float* __restrict__ x1,
    float* __restrict__ out)
{
    const int nt = blockIdx.x, otile = blockIdx.y, b = blockIdx.z;
    const int wave = threadIdx.x >> 6, lane = threadIdx.x & 63;
    const int g = lane >> 4, l15 = lane & 15;
    const int o0 = otile * 64 + wave * 16;

    bf16x8 a[8];
    const float* wrow = pw + (size_t)(o0 + l15) * C;
#pragma unroll
    for (int cb = 0; cb < 8; ++cb) {
        const float4* wp = reinterpret_cast<const float4*>(wrow + cb * 32 + 8 * g);
        float4 w0 = wp[0], w1 = wp[1];
        bf16x8 t = { (__bf16)w0.x, (__bf16)w0.y, (__bf16)w0.z, (__bf16)w0.w,
                     (__bf16)w1.x, (__bf16)w1.y, (__bf16)w1.z, (__bf16)w1.w };
        a[cb] = t;
    }
    const float gb = gate_b[0];

#pragma unroll
    for (int ns = 0; ns < 4; ++ns) {
        const int n0 = nt * 64 + ns * 16;
        f32x4 acc = {0.f, 0.f, 0.f, 0.f};
        const bf16* orow = Ot + ((size_t)b * NPIX + n0 + l15) * C;
#pragma unroll
        for (int cb = 0; cb < 8; ++cb) {
            bf16x8 bf = *reinterpret_cast<const bf16x8*>(orow + cb * 32 + 8 * g);
            acc = __builtin_amdgcn_mfma_f32_16x16x32_bf16(a[cb], bf, acc, 0, 0, 0);
        }
        float gsum = gate_ws[b * NPIX + n0 + l15];
        float gate = 1.f / (1.f + __expf(-(gsum + gb)));
#pragma unroll
        for (int r = 0; r < 4; ++r) {
            int oc = o0 + 4 * g + r;
            float scl = bn_g[oc] * rsqrtf(bn_v[oc] + EPSV);
            float v = (acc[r] + pb[oc] - bn_m[oc]) * scl + bn_b[oc];
            v = fmaxf(v, 0.f);
            size_t idx = ((size_t)b * C + oc) * NPIX + n0 + l15;
            out[idx] = x1[idx] + gate * v;
        }
    }
}

// ---------------------------------------------------------------------------
extern "C" void kernel_launch(void* const* d_in, const int* in_sizes, int n_in,
                              void* d_out, int out_size, void* d_ws, size_t ws_size,
                              hipStream_t stream)
{
    const float* x1  = (const float*)d_in[0];
    const float* x2  = (const float*)d_in[1];
    const float* q_w = (const float*)d_in[2];
    const float* q_b = (const float*)d_in[3];
    const float* k_w = (const float*)d_in[4];
    const float* k_b = (const float*)d_in[5];
    const float* v_w = (const float*)d_in[6];
    const float* v_b = (const float*)d_in[7];
    const float* p_w = (const float*)d_in[8];
    const float* p_b = (const float*)d_in[9];
    const float* bn_g = (const float*)d_in[10];
    const float* bn_b = (const float*)d_in[11];
    const float* bn_m = (const float*)d_in[12];
    const float* bn_v = (const float*)d_in[13];
    const float* g_w  = (const float*)d_in[14];
    const float* g_b  = (const float*)d_in[15];
    float* out = (float*)d_out;

    const size_t szBF = (size_t)NB * NPIX * C * sizeof(bf16);   // 8 MiB
    char* p = (char*)d_ws;
    bf16* xt1 = (bf16*)p; p += szBF;
    bf16* xt2 = (bf16*)p; p += szBF;
    bf16* Qt  = (bf16*)p; p += szBF;
    bf16* Kt  = (bf16*)p; p += szBF;
    bf16* Vv  = (bf16*)p; p += szBF;
    float* gate_ws = (float*)p;

    bf16*   Ot    = xt1;             // xt1 dead after k_qkv
    float2* mlws  = (float2*)xt2;    // xt2 dead after k_qkv (256 KB used)
    bf16*   Opart = (bf16*)d_out;    // 16 MB scratch: 2 halves x 8 MB; k_proj overwrites

    hipFuncSetAttribute((const void*)k_attn,
                        hipFuncAttributeMaxDynamicSharedMemorySize, SMEM_ATTN);

    hipMemsetAsync(gate_ws, 0, (size_t)NB * NPIX * sizeof(float), stream);
    k_transpose<<<dim3(64, 4, 8),  256, 0, stream>>>(x1, x2, g_w, xt1, xt2, gate_ws);
    k_qkv     <<<dim3(64, 4, 12), 256, 0, stream>>>(xt1, xt2, q_w, q_b, k_w, k_b,
                                                    v_w, v_b, Qt, Kt, Vv);
    k_attn    <<<dim3(512), 256, SMEM_ATTN, stream>>>(Qt, Kt, Vv, Opart, mlws);
    k_combine <<<dim3(2048), 256, 0, stream>>>(Opart, mlws, Ot);
    k_proj    <<<dim3(64, 4, 4),  256, 0, stream>>>(Ot, p_w, p_b, bn_g, bn_b, bn_m,
                                                    bn_v, gate_ws, g_b, x1, out);
}